// Round 1
// baseline (1221.974 us; speedup 1.0000x reference)
//
#include <hip/hip_runtime.h>

#define N_NODES 100000
#define N_EDGES 1600000
#define IN_CH   128
#define NHID    64
#define OUT_CH  40
#define NBLK    391   // ceil(N_NODES/256)

// ---------------- CSR build ----------------

__global__ __launch_bounds__(256) void k_count(const int* __restrict__ ei, int* __restrict__ cnt) {
    int e = blockIdx.x * 256 + threadIdx.x;
    if (e < N_EDGES) atomicAdd(&cnt[ei[N_EDGES + e]], 1);
}

__global__ __launch_bounds__(256) void k_scan1(const int* __restrict__ cnt,
                                               int* __restrict__ rowptr,
                                               int* __restrict__ bsum) {
    __shared__ int s[256];
    int t = threadIdx.x;
    int n = blockIdx.x * 256 + t;
    int v = (n < N_NODES) ? cnt[n] : 0;
    s[t] = v;
    __syncthreads();
    for (int off = 1; off < 256; off <<= 1) {
        int add = (t >= off) ? s[t - off] : 0;
        __syncthreads();
        s[t] += add;
        __syncthreads();
    }
    int incl = s[t];
    if (n < N_NODES) rowptr[n] = incl - v;   // exclusive prefix (block-local)
    if (t == 255) bsum[blockIdx.x] = incl;   // block total
}

__global__ __launch_bounds__(512) void k_scan2(int* __restrict__ bsum) {
    __shared__ int s[512];
    int t = threadIdx.x;
    int v = (t < NBLK) ? bsum[t] : 0;
    s[t] = v;
    __syncthreads();
    for (int off = 1; off < 512; off <<= 1) {
        int add = (t >= off) ? s[t - off] : 0;
        __syncthreads();
        s[t] += add;
        __syncthreads();
    }
    if (t < NBLK) bsum[t] = s[t] - v;        // exclusive
}

__global__ __launch_bounds__(256) void k_scan3(const int* __restrict__ cnt,
                                               const int* __restrict__ bsum,
                                               int* __restrict__ rowptr,
                                               int* __restrict__ cursor,
                                               float* __restrict__ dinv) {
    int n = blockIdx.x * 256 + threadIdx.x;
    if (n < N_NODES) {
        int rp = rowptr[n] + bsum[n >> 8];
        rowptr[n] = rp;
        cursor[n] = rp;
        int c = cnt[n];
        dinv[n] = (c > 0) ? rsqrtf((float)c) : 0.0f;
    }
    if (blockIdx.x == 0 && threadIdx.x == 0) rowptr[N_NODES] = N_EDGES;
}

__global__ __launch_bounds__(256) void k_scatter(const int* __restrict__ ei,
                                                 const float* __restrict__ dinv,
                                                 int* __restrict__ cursor,
                                                 int2* __restrict__ e8) {
    int e = blockIdx.x * 256 + threadIdx.x;
    if (e < N_EDGES) {
        int r = ei[e];
        int c = ei[N_EDGES + e];
        int pos = atomicAdd(&cursor[c], 1);
        float w = dinv[r] * dinv[c];
        e8[pos] = make_int2(r, __float_as_int(w));
    }
}

// ---------------- fc1: h = relu(x @ fc1_w^T + b), write h and h0 ----------------

__global__ __launch_bounds__(256) void k_fc1(const float* __restrict__ x,
                                             const float* __restrict__ w,
                                             const float* __restrict__ b,
                                             float* __restrict__ h,
                                             float* __restrict__ h0) {
    __shared__ float wT[IN_CH * NHID];     // [k][o]
    __shared__ float xs[64 * 132];         // 64 nodes x 128 (+4 pad)
    int t = threadIdx.x;
    int nodeBase = blockIdx.x * 64;

    for (int id = t; id < IN_CH * NHID; id += 256) {
        int o = id >> 7, k = id & 127;
        wT[k * NHID + o] = w[id];
    }
    {
        int nl = t >> 2, seg = t & 3;
        int n = nodeBase + nl;
        float4* dst = (float4*)(xs + nl * 132 + seg * 32);
        if (n < N_NODES) {
            const float4* src = (const float4*)(x + (size_t)n * IN_CH + seg * 32);
#pragma unroll
            for (int q = 0; q < 8; q++) dst[q] = src[q];
        } else {
            float4 z = {0.f, 0.f, 0.f, 0.f};
#pragma unroll
            for (int q = 0; q < 8; q++) dst[q] = z;
        }
    }
    __syncthreads();

    int tx = t & 15, ty = t >> 4;
    int o0 = tx * 4, n0 = ty * 4;
    float c[4][4];
#pragma unroll
    for (int i = 0; i < 4; i++)
#pragma unroll
        for (int j = 0; j < 4; j++) c[i][j] = 0.f;

#pragma unroll 8
    for (int k = 0; k < IN_CH; k++) {
        float4 bv = *(const float4*)&wT[k * NHID + o0];
#pragma unroll
        for (int i = 0; i < 4; i++) {
            float a = xs[(n0 + i) * 132 + k];
            c[i][0] += a * bv.x; c[i][1] += a * bv.y;
            c[i][2] += a * bv.z; c[i][3] += a * bv.w;
        }
    }
    float4 bias = *(const float4*)&b[o0];
#pragma unroll
    for (int i = 0; i < 4; i++) {
        int n = nodeBase + n0 + i;
        if (n < N_NODES) {
            float4 v;
            v.x = fmaxf(c[i][0] + bias.x, 0.f);
            v.y = fmaxf(c[i][1] + bias.y, 0.f);
            v.z = fmaxf(c[i][2] + bias.z, 0.f);
            v.w = fmaxf(c[i][3] + bias.w, 0.f);
            *(float4*)&h [(size_t)n * NHID + o0] = v;
            *(float4*)&h0[(size_t)n * NHID + o0] = v;
        }
    }
}

// ------- fused GCN2Conv layer: agg -> mix -> GEMM(64x64) -> relu -------

__global__ __launch_bounds__(256) void k_conv(const float* __restrict__ hin,
                                              const float* __restrict__ h0,
                                              const int* __restrict__ rowptr,
                                              const int2* __restrict__ e8,
                                              const float* __restrict__ W,   // [c][o] 64x64
                                              float* __restrict__ hout) {
    __shared__ float wT[NHID * NHID];   // direct copy, [c][o]
    __shared__ float mix[64 * 68];      // 64 nodes x 64 (+4 pad)
    int t = threadIdx.x;
    int lane = t & 63, wid = t >> 6;
    int nodeBase = blockIdx.x * 64;

    for (int id = t; id < NHID * NHID; id += 256) wT[id] = W[id];

    // phase 1: per-wave aggregation, lane = channel
    for (int q = 0; q < 16; q++) {
        int nl = wid * 16 + q;
        int n = nodeBase + nl;
        float m = 0.f;
        if (n < N_NODES) {
            int s = rowptr[n], e = rowptr[n + 1];
            float acc = 0.f;
            int2 pre = make_int2(0, 0);
            if (s < e) pre = e8[s];
            for (int j = s; j < e; ++j) {
                int2 cur = pre;
                if (j + 1 < e) pre = e8[j + 1];           // prefetch next edge meta
                acc += __int_as_float(cur.y) * hin[cur.x * NHID + lane];
            }
            m = 0.9f * acc + 0.1f * h0[n * NHID + lane];
        }
        mix[nl * 68 + lane] = m;
    }
    __syncthreads();

    // phase 2: 64x64 tile GEMM, 4x4 acc per thread
    int tx = t & 15, ty = t >> 4;
    int o0 = tx * 4, n0 = ty * 4;
    float c[4][4];
#pragma unroll
    for (int i = 0; i < 4; i++)
#pragma unroll
        for (int j = 0; j < 4; j++) c[i][j] = 0.f;

#pragma unroll 8
    for (int k = 0; k < NHID; k++) {
        float4 bv = *(const float4*)&wT[k * NHID + o0];
#pragma unroll
        for (int i = 0; i < 4; i++) {
            float a = mix[(n0 + i) * 68 + k];
            c[i][0] += a * bv.x; c[i][1] += a * bv.y;
            c[i][2] += a * bv.z; c[i][3] += a * bv.w;
        }
    }
#pragma unroll
    for (int i = 0; i < 4; i++) {
        int n = nodeBase + n0 + i;
        if (n < N_NODES) {
            float4 v;
            v.x = fmaxf(c[i][0], 0.f);
            v.y = fmaxf(c[i][1], 0.f);
            v.z = fmaxf(c[i][2], 0.f);
            v.w = fmaxf(c[i][3], 0.f);
            *(float4*)&hout[(size_t)n * NHID + o0] = v;
        }
    }
}

// ---------------- fc2: out = h @ fc2_w^T + b (no relu) ----------------

__global__ __launch_bounds__(256) void k_fc2(const float* __restrict__ h,
                                             const float* __restrict__ w,
                                             const float* __restrict__ b,
                                             float* __restrict__ out) {
    __shared__ float wT[NHID * OUT_CH];  // [k][o] 64x40
    __shared__ float hs[64 * 68];
    int t = threadIdx.x;
    int nodeBase = blockIdx.x * 64;

    for (int id = t; id < NHID * OUT_CH; id += 256) {
        int o = id >> 6, k = id & 63;
        wT[k * OUT_CH + o] = w[id];
    }
    {
        int nl = t >> 2, seg = t & 3;
        int n = nodeBase + nl;
        float4* dst = (float4*)(hs + nl * 68 + seg * 16);
        if (n < N_NODES) {
            const float4* src = (const float4*)(h + (size_t)n * NHID + seg * 16);
#pragma unroll
            for (int q = 0; q < 4; q++) dst[q] = src[q];
        } else {
            float4 z = {0.f, 0.f, 0.f, 0.f};
#pragma unroll
            for (int q = 0; q < 4; q++) dst[q] = z;
        }
    }
    __syncthreads();

    if (t < 160) {
        int tx = t % 10, ty = t / 10;
        int o0 = tx * 4, n0 = ty * 4;
        float c[4][4];
#pragma unroll
        for (int i = 0; i < 4; i++)
#pragma unroll
            for (int j = 0; j < 4; j++) c[i][j] = 0.f;

#pragma unroll 8
        for (int k = 0; k < NHID; k++) {
            float4 bv = *(const float4*)&wT[k * OUT_CH + o0];
#pragma unroll
            for (int i = 0; i < 4; i++) {
                float a = hs[(n0 + i) * 68 + k];
                c[i][0] += a * bv.x; c[i][1] += a * bv.y;
                c[i][2] += a * bv.z; c[i][3] += a * bv.w;
            }
        }
        float4 bias = *(const float4*)&b[o0];
#pragma unroll
        for (int i = 0; i < 4; i++) {
            int n = nodeBase + n0 + i;
            if (n < N_NODES) {
                float4 v;
                v.x = c[i][0] + bias.x;
                v.y = c[i][1] + bias.y;
                v.z = c[i][2] + bias.z;
                v.w = c[i][3] + bias.w;
                *(float4*)&out[(size_t)n * OUT_CH + o0] = v;
            }
        }
    }
}

// ---------------- launch ----------------

extern "C" void kernel_launch(void* const* d_in, const int* in_sizes, int n_in,
                              void* d_out, int out_size, void* d_ws, size_t ws_size,
                              hipStream_t stream) {
    const float* x    = (const float*)d_in[0];
    const int*   ei   = (const int*)d_in[1];
    const float* fc1w = (const float*)d_in[3];
    const float* fc1b = (const float*)d_in[4];
    const float* cw   = (const float*)d_in[5];
    const float* fc2w = (const float*)d_in[6];
    const float* fc2b = (const float*)d_in[7];
    float* out = (float*)d_out;

    char* p = (char*)d_ws;
    auto alloc = [&](size_t bytes) { char* r = p; p += (bytes + 255) & ~(size_t)255; return r; };
    float* h      = (float*)alloc((size_t)N_NODES * NHID * 4);
    float* hb     = (float*)alloc((size_t)N_NODES * NHID * 4);
    float* h0     = (float*)alloc((size_t)N_NODES * NHID * 4);
    int2*  e8     = (int2*) alloc((size_t)N_EDGES * 8);
    int*   cnt    = (int*)  alloc((size_t)N_NODES * 4);
    int*   rowptr = (int*)  alloc((size_t)(N_NODES + 1) * 4);
    int*   cursor = (int*)  alloc((size_t)N_NODES * 4);
    float* dinv   = (float*)alloc((size_t)N_NODES * 4);
    int*   bsum   = (int*)  alloc(512 * 4);

    hipMemsetAsync(cnt, 0, (size_t)N_NODES * 4, stream);
    k_count  <<<(N_EDGES + 255) / 256, 256, 0, stream>>>(ei, cnt);
    k_scan1  <<<NBLK, 256, 0, stream>>>(cnt, rowptr, bsum);
    k_scan2  <<<1, 512, 0, stream>>>(bsum);
    k_scan3  <<<NBLK, 256, 0, stream>>>(cnt, bsum, rowptr, cursor, dinv);
    k_scatter<<<(N_EDGES + 255) / 256, 256, 0, stream>>>(ei, dinv, cursor, e8);

    int gb = (N_NODES + 63) / 64;   // 1563
    k_fc1 <<<gb, 256, 0, stream>>>(x, fc1w, fc1b, h, h0);
    k_conv<<<gb, 256, 0, stream>>>(h,  h0, rowptr, e8, cw + 0 * NHID * NHID, hb);
    k_conv<<<gb, 256, 0, stream>>>(hb, h0, rowptr, e8, cw + 1 * NHID * NHID, h);
    k_conv<<<gb, 256, 0, stream>>>(h,  h0, rowptr, e8, cw + 2 * NHID * NHID, hb);
    k_conv<<<gb, 256, 0, stream>>>(hb, h0, rowptr, e8, cw + 3 * NHID * NHID, h);
    k_fc2 <<<gb, 256, 0, stream>>>(h, fc2w, fc2b, out);
}

// Round 2
// 799.583 us; speedup vs baseline: 1.5283x; 1.5283x over previous
//
#include <hip/hip_runtime.h>

#define N_NODES 100000
#define N_EDGES 1600000
#define IN_CH   128
#define NHID    64
#define OUT_CH  40
#define NBLK    391   // ceil(N_NODES/256)

// ---------------- CSR build ----------------

__global__ __launch_bounds__(256) void k_count(const int* __restrict__ ei, int* __restrict__ cnt) {
    int e = blockIdx.x * 256 + threadIdx.x;
    if (e < N_EDGES) atomicAdd(&cnt[ei[N_EDGES + e]], 1);
}

__global__ __launch_bounds__(256) void k_scan1(const int* __restrict__ cnt,
                                               int* __restrict__ rowptr,
                                               int* __restrict__ bsum) {
    __shared__ int s[256];
    int t = threadIdx.x;
    int n = blockIdx.x * 256 + t;
    int v = (n < N_NODES) ? cnt[n] : 0;
    s[t] = v;
    __syncthreads();
    for (int off = 1; off < 256; off <<= 1) {
        int add = (t >= off) ? s[t - off] : 0;
        __syncthreads();
        s[t] += add;
        __syncthreads();
    }
    int incl = s[t];
    if (n < N_NODES) rowptr[n] = incl - v;   // exclusive prefix (block-local)
    if (t == 255) bsum[blockIdx.x] = incl;   // block total
}

__global__ __launch_bounds__(512) void k_scan2(int* __restrict__ bsum) {
    __shared__ int s[512];
    int t = threadIdx.x;
    int v = (t < NBLK) ? bsum[t] : 0;
    s[t] = v;
    __syncthreads();
    for (int off = 1; off < 512; off <<= 1) {
        int add = (t >= off) ? s[t - off] : 0;
        __syncthreads();
        s[t] += add;
        __syncthreads();
    }
    if (t < NBLK) bsum[t] = s[t] - v;        // exclusive
}

__global__ __launch_bounds__(256) void k_scan3(const int* __restrict__ cnt,
                                               const int* __restrict__ bsum,
                                               int* __restrict__ rowptr,
                                               int* __restrict__ cursor,
                                               float* __restrict__ dinv) {
    int n = blockIdx.x * 256 + threadIdx.x;
    if (n < N_NODES) {
        int rp = rowptr[n] + bsum[n >> 8];
        rowptr[n] = rp;
        cursor[n] = rp;
        int c = cnt[n];
        dinv[n] = (c > 0) ? rsqrtf((float)c) : 0.0f;
    }
    if (blockIdx.x == 0 && threadIdx.x == 0) rowptr[N_NODES] = N_EDGES;
}

__global__ __launch_bounds__(256) void k_scatter(const int* __restrict__ ei,
                                                 const float* __restrict__ dinv,
                                                 int* __restrict__ cursor,
                                                 int2* __restrict__ e8) {
    int e = blockIdx.x * 256 + threadIdx.x;
    if (e < N_EDGES) {
        int r = ei[e];
        int c = ei[N_EDGES + e];
        int pos = atomicAdd(&cursor[c], 1);
        float w = dinv[r] * dinv[c];
        e8[pos] = make_int2(r, __float_as_int(w));
    }
}

// ---------------- fc1: h = relu(x @ fc1_w^T + b), write h and h0 ----------------

__global__ __launch_bounds__(256) void k_fc1(const float* __restrict__ x,
                                             const float* __restrict__ w,
                                             const float* __restrict__ b,
                                             float* __restrict__ h,
                                             float* __restrict__ h0) {
    __shared__ float wT[IN_CH * NHID];     // [k][o]
    __shared__ float xs[64 * 132];         // 64 nodes x 128 (+4 pad; 33 float4 stride)
    int t = threadIdx.x;
    int nodeBase = blockIdx.x * 64;

    for (int id = t; id < IN_CH * NHID; id += 256) {
        int o = id >> 7, k = id & 127;
        wT[k * NHID + o] = w[id];
    }
    {
        int nl = t >> 2, seg = t & 3;
        int n = nodeBase + nl;
        float4* dst = (float4*)(xs + nl * 132 + seg * 32);
        if (n < N_NODES) {
            const float4* src = (const float4*)(x + (size_t)n * IN_CH + seg * 32);
#pragma unroll
            for (int q = 0; q < 8; q++) dst[q] = src[q];
        } else {
            float4 z = {0.f, 0.f, 0.f, 0.f};
#pragma unroll
            for (int q = 0; q < 8; q++) dst[q] = z;
        }
    }
    __syncthreads();

    int tx = t & 15, ty = t >> 4;
    int o0 = tx * 4, n0 = ty * 4;
    float c[4][4];
#pragma unroll
    for (int i = 0; i < 4; i++)
#pragma unroll
        for (int j = 0; j < 4; j++) c[i][j] = 0.f;

#pragma unroll 4
    for (int k = 0; k < IN_CH; k += 4) {
        float4 b0 = *(const float4*)&wT[(k + 0) * NHID + o0];
        float4 b1 = *(const float4*)&wT[(k + 1) * NHID + o0];
        float4 b2 = *(const float4*)&wT[(k + 2) * NHID + o0];
        float4 b3 = *(const float4*)&wT[(k + 3) * NHID + o0];
#pragma unroll
        for (int i = 0; i < 4; i++) {
            float4 a = *(const float4*)&xs[(n0 + i) * 132 + k];
            c[i][0] = fmaf(a.x, b0.x, fmaf(a.y, b1.x, fmaf(a.z, b2.x, fmaf(a.w, b3.x, c[i][0]))));
            c[i][1] = fmaf(a.x, b0.y, fmaf(a.y, b1.y, fmaf(a.z, b2.y, fmaf(a.w, b3.y, c[i][1]))));
            c[i][2] = fmaf(a.x, b0.z, fmaf(a.y, b1.z, fmaf(a.z, b2.z, fmaf(a.w, b3.z, c[i][2]))));
            c[i][3] = fmaf(a.x, b0.w, fmaf(a.y, b1.w, fmaf(a.z, b2.w, fmaf(a.w, b3.w, c[i][3]))));
        }
    }
    float4 bias = *(const float4*)&b[o0];
#pragma unroll
    for (int i = 0; i < 4; i++) {
        int n = nodeBase + n0 + i;
        if (n < N_NODES) {
            float4 v;
            v.x = fmaxf(c[i][0] + bias.x, 0.f);
            v.y = fmaxf(c[i][1] + bias.y, 0.f);
            v.z = fmaxf(c[i][2] + bias.z, 0.f);
            v.w = fmaxf(c[i][3] + bias.w, 0.f);
            *(float4*)&h [(size_t)n * NHID + o0] = v;
            *(float4*)&h0[(size_t)n * NHID + o0] = v;
        }
    }
}

// ------- fused GCN2Conv layer: agg (8-deep MLP) -> mix -> GEMM(64x64) -> relu -------

__global__ __launch_bounds__(256) void k_conv(const float* __restrict__ hin,
                                              const float* __restrict__ h0,
                                              const int* __restrict__ rowptr,
                                              const int2* __restrict__ e8,
                                              const float* __restrict__ W,   // [c][o] 64x64
                                              float* __restrict__ hout) {
    __shared__ float wT[NHID * NHID];   // direct copy, [c][o]
    __shared__ float mix[64 * 68];      // 64 nodes x 64 (+4 pad; 17 float4 stride)
    int t = threadIdx.x;
    int lane = t & 63, wid = t >> 6;
    int nodeBase = blockIdx.x * 64;

    for (int id = t; id < NHID * NHID; id += 256) wT[id] = W[id];

    // phase 1: per-wave aggregation, lane = channel, 8 gathers in flight
    for (int q = 0; q < 16; q++) {
        int nl = wid * 16 + q;
        int n = nodeBase + nl;
        float m = 0.f;
        if (n < N_NODES) {
            int s = rowptr[n], e = rowptr[n + 1];
            float acc = 0.f;
            int j = s;
            for (; j + 8 <= e; j += 8) {
                int2 m0 = e8[j + 0], m1 = e8[j + 1], m2 = e8[j + 2], m3 = e8[j + 3];
                int2 m4 = e8[j + 4], m5 = e8[j + 5], m6 = e8[j + 6], m7 = e8[j + 7];
                float v0 = hin[m0.x * NHID + lane];
                float v1 = hin[m1.x * NHID + lane];
                float v2 = hin[m2.x * NHID + lane];
                float v3 = hin[m3.x * NHID + lane];
                float v4 = hin[m4.x * NHID + lane];
                float v5 = hin[m5.x * NHID + lane];
                float v6 = hin[m6.x * NHID + lane];
                float v7 = hin[m7.x * NHID + lane];
                acc = fmaf(__int_as_float(m0.y), v0, acc);
                acc = fmaf(__int_as_float(m1.y), v1, acc);
                acc = fmaf(__int_as_float(m2.y), v2, acc);
                acc = fmaf(__int_as_float(m3.y), v3, acc);
                acc = fmaf(__int_as_float(m4.y), v4, acc);
                acc = fmaf(__int_as_float(m5.y), v5, acc);
                acc = fmaf(__int_as_float(m6.y), v6, acc);
                acc = fmaf(__int_as_float(m7.y), v7, acc);
            }
            if (j + 4 <= e) {
                int2 m0 = e8[j + 0], m1 = e8[j + 1], m2 = e8[j + 2], m3 = e8[j + 3];
                float v0 = hin[m0.x * NHID + lane];
                float v1 = hin[m1.x * NHID + lane];
                float v2 = hin[m2.x * NHID + lane];
                float v3 = hin[m3.x * NHID + lane];
                acc = fmaf(__int_as_float(m0.y), v0, acc);
                acc = fmaf(__int_as_float(m1.y), v1, acc);
                acc = fmaf(__int_as_float(m2.y), v2, acc);
                acc = fmaf(__int_as_float(m3.y), v3, acc);
                j += 4;
            }
            for (; j < e; ++j) {
                int2 mm = e8[j];
                acc = fmaf(__int_as_float(mm.y), hin[mm.x * NHID + lane], acc);
            }
            m = 0.9f * acc + 0.1f * h0[n * NHID + lane];
        }
        mix[nl * 68 + lane] = m;
    }
    __syncthreads();

    // phase 2: 64x64 tile GEMM, 4x4 acc per thread, k-vectorized LDS reads
    int tx = t & 15, ty = t >> 4;
    int o0 = tx * 4, n0 = ty * 4;
    float c[4][4];
#pragma unroll
    for (int i = 0; i < 4; i++)
#pragma unroll
        for (int j = 0; j < 4; j++) c[i][j] = 0.f;

#pragma unroll 4
    for (int k = 0; k < NHID; k += 4) {
        float4 b0 = *(const float4*)&wT[(k + 0) * NHID + o0];
        float4 b1 = *(const float4*)&wT[(k + 1) * NHID + o0];
        float4 b2 = *(const float4*)&wT[(k + 2) * NHID + o0];
        float4 b3 = *(const float4*)&wT[(k + 3) * NHID + o0];
#pragma unroll
        for (int i = 0; i < 4; i++) {
            float4 a = *(const float4*)&mix[(n0 + i) * 68 + k];
            c[i][0] = fmaf(a.x, b0.x, fmaf(a.y, b1.x, fmaf(a.z, b2.x, fmaf(a.w, b3.x, c[i][0]))));
            c[i][1] = fmaf(a.x, b0.y, fmaf(a.y, b1.y, fmaf(a.z, b2.y, fmaf(a.w, b3.y, c[i][1]))));
            c[i][2] = fmaf(a.x, b0.z, fmaf(a.y, b1.z, fmaf(a.z, b2.z, fmaf(a.w, b3.z, c[i][2]))));
            c[i][3] = fmaf(a.x, b0.w, fmaf(a.y, b1.w, fmaf(a.z, b2.w, fmaf(a.w, b3.w, c[i][3]))));
        }
    }
#pragma unroll
    for (int i = 0; i < 4; i++) {
        int n = nodeBase + n0 + i;
        if (n < N_NODES) {
            float4 v;
            v.x = fmaxf(c[i][0], 0.f);
            v.y = fmaxf(c[i][1], 0.f);
            v.z = fmaxf(c[i][2], 0.f);
            v.w = fmaxf(c[i][3], 0.f);
            *(float4*)&hout[(size_t)n * NHID + o0] = v;
        }
    }
}

// ---------------- fc2: out = h @ fc2_w^T + b (no relu) ----------------

__global__ __launch_bounds__(256) void k_fc2(const float* __restrict__ h,
                                             const float* __restrict__ w,
                                             const float* __restrict__ b,
                                             float* __restrict__ out) {
    __shared__ float wT[NHID * 44];      // [k][o] 64x40, padded stride 44 (11 float4)
    __shared__ float hs[64 * 68];
    int t = threadIdx.x;
    int nodeBase = blockIdx.x * 64;

    for (int id = t; id < NHID * OUT_CH; id += 256) {
        int o = id >> 6, k = id & 63;
        wT[k * 44 + o] = w[id];
    }
    {
        int nl = t >> 2, seg = t & 3;
        int n = nodeBase + nl;
        float4* dst = (float4*)(hs + nl * 68 + seg * 16);
        if (n < N_NODES) {
            const float4* src = (const float4*)(h + (size_t)n * NHID + seg * 16);
#pragma unroll
            for (int q = 0; q < 4; q++) dst[q] = src[q];
        } else {
            float4 z = {0.f, 0.f, 0.f, 0.f};
#pragma unroll
            for (int q = 0; q < 4; q++) dst[q] = z;
        }
    }
    __syncthreads();

    if (t < 160) {
        int tx = t % 10, ty = t / 10;
        int o0 = tx * 4, n0 = ty * 4;
        float c[4][4];
#pragma unroll
        for (int i = 0; i < 4; i++)
#pragma unroll
            for (int j = 0; j < 4; j++) c[i][j] = 0.f;

#pragma unroll 4
        for (int k = 0; k < NHID; k += 4) {
            float4 b0 = *(const float4*)&wT[(k + 0) * 44 + o0];
            float4 b1 = *(const float4*)&wT[(k + 1) * 44 + o0];
            float4 b2 = *(const float4*)&wT[(k + 2) * 44 + o0];
            float4 b3 = *(const float4*)&wT[(k + 3) * 44 + o0];
#pragma unroll
            for (int i = 0; i < 4; i++) {
                float4 a = *(const float4*)&hs[(n0 + i) * 68 + k];
                c[i][0] = fmaf(a.x, b0.x, fmaf(a.y, b1.x, fmaf(a.z, b2.x, fmaf(a.w, b3.x, c[i][0]))));
                c[i][1] = fmaf(a.x, b0.y, fmaf(a.y, b1.y, fmaf(a.z, b2.y, fmaf(a.w, b3.y, c[i][1]))));
                c[i][2] = fmaf(a.x, b0.z, fmaf(a.y, b1.z, fmaf(a.z, b2.z, fmaf(a.w, b3.z, c[i][2]))));
                c[i][3] = fmaf(a.x, b0.w, fmaf(a.y, b1.w, fmaf(a.z, b2.w, fmaf(a.w, b3.w, c[i][3]))));
            }
        }
        float4 bias = *(const float4*)&b[o0];
#pragma unroll
        for (int i = 0; i < 4; i++) {
            int n = nodeBase + n0 + i;
            if (n < N_NODES) {
                float4 v;
                v.x = c[i][0] + bias.x;
                v.y = c[i][1] + bias.y;
                v.z = c[i][2] + bias.z;
                v.w = c[i][3] + bias.w;
                *(float4*)&out[(size_t)n * OUT_CH + o0] = v;
            }
        }
    }
}

// ---------------- launch ----------------

extern "C" void kernel_launch(void* const* d_in, const int* in_sizes, int n_in,
                              void* d_out, int out_size, void* d_ws, size_t ws_size,
                              hipStream_t stream) {
    const float* x    = (const float*)d_in[0];
    const int*   ei   = (const int*)d_in[1];
    const float* fc1w = (const float*)d_in[3];
    const float* fc1b = (const float*)d_in[4];
    const float* cw   = (const float*)d_in[5];
    const float* fc2w = (const float*)d_in[6];
    const float* fc2b = (const float*)d_in[7];
    float* out = (float*)d_out;

    char* p = (char*)d_ws;
    auto alloc = [&](size_t bytes) { char* r = p; p += (bytes + 255) & ~(size_t)255; return r; };
    float* h      = (float*)alloc((size_t)N_NODES * NHID * 4);
    float* hb     = (float*)alloc((size_t)N_NODES * NHID * 4);
    float* h0     = (float*)alloc((size_t)N_NODES * NHID * 4);
    int2*  e8     = (int2*) alloc((size_t)N_EDGES * 8);
    int*   cnt    = (int*)  alloc((size_t)N_NODES * 4);
    int*   rowptr = (int*)  alloc((size_t)(N_NODES + 1) * 4);
    int*   cursor = (int*)  alloc((size_t)N_NODES * 4);
    float* dinv   = (float*)alloc((size_t)N_NODES * 4);
    int*   bsum   = (int*)  alloc(512 * 4);

    hipMemsetAsync(cnt, 0, (size_t)N_NODES * 4, stream);
    k_count  <<<(N_EDGES + 255) / 256, 256, 0, stream>>>(ei, cnt);
    k_scan1  <<<NBLK, 256, 0, stream>>>(cnt, rowptr, bsum);
    k_scan2  <<<1, 512, 0, stream>>>(bsum);
    k_scan3  <<<NBLK, 256, 0, stream>>>(cnt, bsum, rowptr, cursor, dinv);
    k_scatter<<<(N_EDGES + 255) / 256, 256, 0, stream>>>(ei, dinv, cursor, e8);

    int gb = (N_NODES + 63) / 64;   // 1563
    k_fc1 <<<gb, 256, 0, stream>>>(x, fc1w, fc1b, h, h0);
    k_conv<<<gb, 256, 0, stream>>>(h,  h0, rowptr, e8, cw + 0 * NHID * NHID, hb);
    k_conv<<<gb, 256, 0, stream>>>(hb, h0, rowptr, e8, cw + 1 * NHID * NHID, h);
    k_conv<<<gb, 256, 0, stream>>>(h,  h0, rowptr, e8, cw + 2 * NHID * NHID, hb);
    k_conv<<<gb, 256, 0, stream>>>(hb, h0, rowptr, e8, cw + 3 * NHID * NHID, h);
    k_fc2 <<<gb, 256, 0, stream>>>(h, fc2w, fc2b, out);
}

// Round 3
// 619.184 us; speedup vs baseline: 1.9735x; 1.2913x over previous
//
#include <hip/hip_runtime.h>

#define N_NODES 100000
#define N_EDGES 1600000
#define IN_CH   128
#define NHID    64
#define OUT_CH  40
#define NBLK    391   // ceil(N_NODES/256)

// ---------------- CSR build ----------------

__global__ __launch_bounds__(256) void k_count(const int* __restrict__ ei, int* __restrict__ cnt) {
    int e = blockIdx.x * 256 + threadIdx.x;
    if (e < N_EDGES) atomicAdd(&cnt[ei[N_EDGES + e]], 1);
}

__global__ __launch_bounds__(256) void k_scan1(const int* __restrict__ cnt,
                                               int* __restrict__ rowptr,
                                               int* __restrict__ bsum) {
    __shared__ int s[256];
    int t = threadIdx.x;
    int n = blockIdx.x * 256 + t;
    int v = (n < N_NODES) ? cnt[n] : 0;
    s[t] = v;
    __syncthreads();
    for (int off = 1; off < 256; off <<= 1) {
        int add = (t >= off) ? s[t - off] : 0;
        __syncthreads();
        s[t] += add;
        __syncthreads();
    }
    int incl = s[t];
    if (n < N_NODES) rowptr[n] = incl - v;   // exclusive prefix (block-local)
    if (t == 255) bsum[blockIdx.x] = incl;   // block total
}

__global__ __launch_bounds__(512) void k_scan2(int* __restrict__ bsum) {
    __shared__ int s[512];
    int t = threadIdx.x;
    int v = (t < NBLK) ? bsum[t] : 0;
    s[t] = v;
    __syncthreads();
    for (int off = 1; off < 512; off <<= 1) {
        int add = (t >= off) ? s[t - off] : 0;
        __syncthreads();
        s[t] += add;
        __syncthreads();
    }
    if (t < NBLK) bsum[t] = s[t] - v;        // exclusive
}

__global__ __launch_bounds__(256) void k_scan3(const int* __restrict__ cnt,
                                               const int* __restrict__ bsum,
                                               int* __restrict__ rowptr,
                                               int* __restrict__ cursor,
                                               float* __restrict__ dinv) {
    int n = blockIdx.x * 256 + threadIdx.x;
    if (n < N_NODES) {
        int rp = rowptr[n] + bsum[n >> 8];
        rowptr[n] = rp;
        cursor[n] = rp;
        int c = cnt[n];
        dinv[n] = (c > 0) ? rsqrtf((float)c) : 0.0f;
    }
    if (blockIdx.x == 0 && threadIdx.x == 0) rowptr[N_NODES] = N_EDGES;
}

__global__ __launch_bounds__(256) void k_scatter(const int* __restrict__ ei,
                                                 const float* __restrict__ dinv,
                                                 int* __restrict__ cursor,
                                                 int2* __restrict__ e8) {
    int e = blockIdx.x * 256 + threadIdx.x;
    if (e < N_EDGES) {
        int r = ei[e];
        int c = ei[N_EDGES + e];
        int pos = atomicAdd(&cursor[c], 1);
        float w = dinv[r] * dinv[c];
        e8[pos] = make_int2(r, __float_as_int(w));
    }
}

// ---------------- fc1: h0 = relu(x @ fc1_w^T + b) ----------------

__global__ __launch_bounds__(256) void k_fc1(const float* __restrict__ x,
                                             const float* __restrict__ w,
                                             const float* __restrict__ b,
                                             float* __restrict__ h0) {
    __shared__ float wT[IN_CH * NHID];     // [k][o]
    __shared__ float xs[64 * 132];         // 64 nodes x 128 (+4 pad; 33 float4 stride)
    int t = threadIdx.x;
    int nodeBase = blockIdx.x * 64;

    for (int id = t; id < IN_CH * NHID; id += 256) {
        int o = id >> 7, k = id & 127;
        wT[k * NHID + o] = w[id];
    }
    {
        int nl = t >> 2, seg = t & 3;
        int n = nodeBase + nl;
        float4* dst = (float4*)(xs + nl * 132 + seg * 32);
        if (n < N_NODES) {
            const float4* src = (const float4*)(x + (size_t)n * IN_CH + seg * 32);
#pragma unroll
            for (int q = 0; q < 8; q++) dst[q] = src[q];
        } else {
            float4 z = {0.f, 0.f, 0.f, 0.f};
#pragma unroll
            for (int q = 0; q < 8; q++) dst[q] = z;
        }
    }
    __syncthreads();

    int tx = t & 15, ty = t >> 4;
    int o0 = tx * 4, n0 = ty * 4;
    float c[4][4];
#pragma unroll
    for (int i = 0; i < 4; i++)
#pragma unroll
        for (int j = 0; j < 4; j++) c[i][j] = 0.f;

#pragma unroll 4
    for (int k = 0; k < IN_CH; k += 4) {
        float4 b0 = *(const float4*)&wT[(k + 0) * NHID + o0];
        float4 b1 = *(const float4*)&wT[(k + 1) * NHID + o0];
        float4 b2 = *(const float4*)&wT[(k + 2) * NHID + o0];
        float4 b3 = *(const float4*)&wT[(k + 3) * NHID + o0];
#pragma unroll
        for (int i = 0; i < 4; i++) {
            float4 a = *(const float4*)&xs[(n0 + i) * 132 + k];
            c[i][0] = fmaf(a.x, b0.x, fmaf(a.y, b1.x, fmaf(a.z, b2.x, fmaf(a.w, b3.x, c[i][0]))));
            c[i][1] = fmaf(a.x, b0.y, fmaf(a.y, b1.y, fmaf(a.z, b2.y, fmaf(a.w, b3.y, c[i][1]))));
            c[i][2] = fmaf(a.x, b0.z, fmaf(a.y, b1.z, fmaf(a.z, b2.z, fmaf(a.w, b3.z, c[i][2]))));
            c[i][3] = fmaf(a.x, b0.w, fmaf(a.y, b1.w, fmaf(a.z, b2.w, fmaf(a.w, b3.w, c[i][3]))));
        }
    }
    float4 bias = *(const float4*)&b[o0];
#pragma unroll
    for (int i = 0; i < 4; i++) {
        int n = nodeBase + n0 + i;
        if (n < N_NODES) {
            float4 v;
            v.x = fmaxf(c[i][0] + bias.x, 0.f);
            v.y = fmaxf(c[i][1] + bias.y, 0.f);
            v.z = fmaxf(c[i][2] + bias.z, 0.f);
            v.w = fmaxf(c[i][3] + bias.w, 0.f);
            *(float4*)&h0[(size_t)n * NHID + o0] = v;
        }
    }
}

// ------- fused GCN2Conv layer: agg (8-deep MLP) -> mix -> GEMM(64x64) -> relu -------
// wT intentionally NOT staged in LDS: W is 16KB, wave-broadcast reads hit L1.
// LDS = mix only (17408 B) -> 8 blocks/CU wave-cap, 2x the round-2 residency.

template<int U>
__device__ __forceinline__ void agg_step(const int2* __restrict__ e8,
                                         const float* __restrict__ hin,
                                         int lane, int j, float& acc) {
    float v[U], wg[U];
#pragma unroll
    for (int u = 0; u < U; u++) {
        int2 mm = e8[j + u];
        wg[u] = __int_as_float(mm.y);
        v[u] = hin[mm.x * NHID + lane];
    }
#pragma unroll
    for (int u = 0; u < U; u++) acc = fmaf(wg[u], v[u], acc);
}

__global__ __launch_bounds__(256, 8) void k_conv(const float* __restrict__ hin,
                                                 const float* __restrict__ h0,
                                                 const int* __restrict__ rowptr,
                                                 const int2* __restrict__ e8,
                                                 const float* __restrict__ W,   // [c][o] 64x64
                                                 float* __restrict__ hout) {
    __shared__ float mix[64 * 68];      // 64 nodes x 64 (+4 pad; 17 float4 stride)
    int t = threadIdx.x;
    int lane = t & 63, wid = t >> 6;
    int nodeBase = blockIdx.x * 64;

    // phase 1: per-wave aggregation, lane = channel, 8 gathers in flight
    for (int q = 0; q < 16; q++) {
        int nl = wid * 16 + q;
        int n = nodeBase + nl;
        float m = 0.f;
        if (n < N_NODES) {
            int s = rowptr[n], e = rowptr[n + 1];
            float h0v = h0[n * NHID + lane];   // independent, issues early
            float acc = 0.f;
            int j = s;
            for (; j + 8 <= e; j += 8) agg_step<8>(e8, hin, lane, j, acc);
            if (j + 4 <= e) { agg_step<4>(e8, hin, lane, j, acc); j += 4; }
            for (; j < e; ++j) {
                int2 mm = e8[j];
                acc = fmaf(__int_as_float(mm.y), hin[mm.x * NHID + lane], acc);
            }
            m = fmaf(0.9f, acc, 0.1f * h0v);
        }
        mix[nl * 68 + lane] = m;
    }
    __syncthreads();

    // phase 2: 64x64 tile GEMM, 4x4 acc per thread; W rows read via L1 (broadcast)
    int tx = t & 15, ty = t >> 4;
    int o0 = tx * 4, n0 = ty * 4;
    float c[4][4];
#pragma unroll
    for (int i = 0; i < 4; i++)
#pragma unroll
        for (int j = 0; j < 4; j++) c[i][j] = 0.f;

#pragma unroll 4
    for (int k = 0; k < NHID; k += 4) {
        float4 b0 = *(const float4*)&W[(k + 0) * NHID + o0];
        float4 b1 = *(const float4*)&W[(k + 1) * NHID + o0];
        float4 b2 = *(const float4*)&W[(k + 2) * NHID + o0];
        float4 b3 = *(const float4*)&W[(k + 3) * NHID + o0];
#pragma unroll
        for (int i = 0; i < 4; i++) {
            float4 a = *(const float4*)&mix[(n0 + i) * 68 + k];
            c[i][0] = fmaf(a.x, b0.x, fmaf(a.y, b1.x, fmaf(a.z, b2.x, fmaf(a.w, b3.x, c[i][0]))));
            c[i][1] = fmaf(a.x, b0.y, fmaf(a.y, b1.y, fmaf(a.z, b2.y, fmaf(a.w, b3.y, c[i][1]))));
            c[i][2] = fmaf(a.x, b0.z, fmaf(a.y, b1.z, fmaf(a.z, b2.z, fmaf(a.w, b3.z, c[i][2]))));
            c[i][3] = fmaf(a.x, b0.w, fmaf(a.y, b1.w, fmaf(a.z, b2.w, fmaf(a.w, b3.w, c[i][3]))));
        }
    }
#pragma unroll
    for (int i = 0; i < 4; i++) {
        int n = nodeBase + n0 + i;
        if (n < N_NODES) {
            float4 v;
            v.x = fmaxf(c[i][0], 0.f);
            v.y = fmaxf(c[i][1], 0.f);
            v.z = fmaxf(c[i][2], 0.f);
            v.w = fmaxf(c[i][3], 0.f);
            *(float4*)&hout[(size_t)n * NHID + o0] = v;
        }
    }
}

// ---------------- fc2: out = h @ fc2_w^T + b (no relu) ----------------

__global__ __launch_bounds__(256) void k_fc2(const float* __restrict__ h,
                                             const float* __restrict__ w,
                                             const float* __restrict__ b,
                                             float* __restrict__ out) {
    __shared__ float wT[NHID * 44];      // [k][o] 64x40, padded stride 44 (11 float4)
    __shared__ float hs[64 * 68];
    int t = threadIdx.x;
    int nodeBase = blockIdx.x * 64;

    for (int id = t; id < NHID * OUT_CH; id += 256) {
        int o = id >> 6, k = id & 63;
        wT[k * 44 + o] = w[id];
    }
    {
        int nl = t >> 2, seg = t & 3;
        int n = nodeBase + nl;
        float4* dst = (float4*)(hs + nl * 68 + seg * 16);
        if (n < N_NODES) {
            const float4* src = (const float4*)(h + (size_t)n * NHID + seg * 16);
#pragma unroll
            for (int q = 0; q < 4; q++) dst[q] = src[q];
        } else {
            float4 z = {0.f, 0.f, 0.f, 0.f};
#pragma unroll
            for (int q = 0; q < 4; q++) dst[q] = z;
        }
    }
    __syncthreads();

    if (t < 160) {
        int tx = t % 10, ty = t / 10;
        int o0 = tx * 4, n0 = ty * 4;
        float c[4][4];
#pragma unroll
        for (int i = 0; i < 4; i++)
#pragma unroll
            for (int j = 0; j < 4; j++) c[i][j] = 0.f;

#pragma unroll 4
        for (int k = 0; k < NHID; k += 4) {
            float4 b0 = *(const float4*)&wT[(k + 0) * 44 + o0];
            float4 b1 = *(const float4*)&wT[(k + 1) * 44 + o0];
            float4 b2 = *(const float4*)&wT[(k + 2) * 44 + o0];
            float4 b3 = *(const float4*)&wT[(k + 3) * 44 + o0];
#pragma unroll
            for (int i = 0; i < 4; i++) {
                float4 a = *(const float4*)&hs[(n0 + i) * 68 + k];
                c[i][0] = fmaf(a.x, b0.x, fmaf(a.y, b1.x, fmaf(a.z, b2.x, fmaf(a.w, b3.x, c[i][0]))));
                c[i][1] = fmaf(a.x, b0.y, fmaf(a.y, b1.y, fmaf(a.z, b2.y, fmaf(a.w, b3.y, c[i][1]))));
                c[i][2] = fmaf(a.x, b0.z, fmaf(a.y, b1.z, fmaf(a.z, b2.z, fmaf(a.w, b3.z, c[i][2]))));
                c[i][3] = fmaf(a.x, b0.w, fmaf(a.y, b1.w, fmaf(a.z, b2.w, fmaf(a.w, b3.w, c[i][3]))));
            }
        }
        float4 bias = *(const float4*)&b[o0];
#pragma unroll
        for (int i = 0; i < 4; i++) {
            int n = nodeBase + n0 + i;
            if (n < N_NODES) {
                float4 v;
                v.x = c[i][0] + bias.x;
                v.y = c[i][1] + bias.y;
                v.z = c[i][2] + bias.z;
                v.w = c[i][3] + bias.w;
                *(float4*)&out[(size_t)n * OUT_CH + o0] = v;
            }
        }
    }
}

// ---------------- launch ----------------

extern "C" void kernel_launch(void* const* d_in, const int* in_sizes, int n_in,
                              void* d_out, int out_size, void* d_ws, size_t ws_size,
                              hipStream_t stream) {
    const float* x    = (const float*)d_in[0];
    const int*   ei   = (const int*)d_in[1];
    const float* fc1w = (const float*)d_in[3];
    const float* fc1b = (const float*)d_in[4];
    const float* cw   = (const float*)d_in[5];
    const float* fc2w = (const float*)d_in[6];
    const float* fc2b = (const float*)d_in[7];
    float* out = (float*)d_out;

    char* p = (char*)d_ws;
    auto alloc = [&](size_t bytes) { char* r = p; p += (bytes + 255) & ~(size_t)255; return r; };
    float* h      = (float*)alloc((size_t)N_NODES * NHID * 4);
    float* hb     = (float*)alloc((size_t)N_NODES * NHID * 4);
    float* h0     = (float*)alloc((size_t)N_NODES * NHID * 4);
    int2*  e8     = (int2*) alloc((size_t)N_EDGES * 8);
    int*   cnt    = (int*)  alloc((size_t)N_NODES * 4);
    int*   rowptr = (int*)  alloc((size_t)(N_NODES + 1) * 4);
    int*   cursor = (int*)  alloc((size_t)N_NODES * 4);
    float* dinv   = (float*)alloc((size_t)N_NODES * 4);
    int*   bsum   = (int*)  alloc(512 * 4);

    hipMemsetAsync(cnt, 0, (size_t)N_NODES * 4, stream);
    k_count  <<<(N_EDGES + 255) / 256, 256, 0, stream>>>(ei, cnt);
    k_scan1  <<<NBLK, 256, 0, stream>>>(cnt, rowptr, bsum);
    k_scan2  <<<1, 512, 0, stream>>>(bsum);
    k_scan3  <<<NBLK, 256, 0, stream>>>(cnt, bsum, rowptr, cursor, dinv);
    k_scatter<<<(N_EDGES + 255) / 256, 256, 0, stream>>>(ei, dinv, cursor, e8);

    int gb = (N_NODES + 63) / 64;   // 1563
    k_fc1 <<<gb, 256, 0, stream>>>(x, fc1w, fc1b, h0);
    k_conv<<<gb, 256, 0, stream>>>(h0, h0, rowptr, e8, cw + 0 * NHID * NHID, hb);
    k_conv<<<gb, 256, 0, stream>>>(hb, h0, rowptr, e8, cw + 1 * NHID * NHID, h);
    k_conv<<<gb, 256, 0, stream>>>(h,  h0, rowptr, e8, cw + 2 * NHID * NHID, hb);
    k_conv<<<gb, 256, 0, stream>>>(hb, h0, rowptr, e8, cw + 3 * NHID * NHID, h);
    k_fc2 <<<gb, 256, 0, stream>>>(h, fc2w, fc2b, out);
}